// Round 6
// baseline (801.289 us; speedup 1.0000x reference)
//
#include <hip/hip_runtime.h>
#include <hip/hip_bf16.h>

#define N_NODES 100000
#define N_EDGES 1200000

typedef __attribute__((ext_vector_type(8))) short bfrag;
typedef __attribute__((ext_vector_type(4))) float ffrag;

union FragU { uint4 v; uint32_t u[4]; bfrag f; };

__device__ __forceinline__ ushort bfbits(float a) {
  union { __hip_bfloat16 h; ushort u; } c; c.h = __float2bfloat16(a); return c.u;
}
__device__ __forceinline__ uint32_t pkbf(float a, float b) {
  union { __hip_bfloat162 h; uint32_t u; } c;
  c.h = __float22bfloat162_rn(float2{a, b}); return c.u;
}
__device__ __forceinline__ uint32_t mul2bf(uint32_t a, uint32_t b) {
  union { uint32_t u; __hip_bfloat162 h; } x, y, r;
  x.u = a; y.u = b; r.h = __hmul2(x.h, y.h); return r.u;
}
__device__ __forceinline__ float bflo(uint32_t u) { return __int_as_float(u << 16); }
__device__ __forceinline__ float bfhi(uint32_t u) { return __int_as_float(u & 0xffff0000u); }

// ---------------- x -> bf16 ----------------

__global__ void cvt_k(const float* __restrict__ x, ushort* __restrict__ xb, int n2) {
  int i = blockIdx.x * blockDim.x + threadIdx.x;   // n2 = N*32 (pairs)
  if (i < n2) {
    float2 v = ((const float2*)x)[i];
    ((uint32_t*)xb)[i] = pkbf(v.x, v.y);
  }
}

// ---------------- CSR build ----------------

__global__ void hist_k(const int* __restrict__ ei, int* __restrict__ deg,
                       int* __restrict__ rank, int E) {
  int e = blockIdx.x * blockDim.x + threadIdx.x;
  if (e < E) rank[e] = atomicAdd(&deg[ei[E + e]], 1);
}

__global__ __launch_bounds__(1024) void scan1_k(const int* __restrict__ deg,
                                                int* __restrict__ off,
                                                int* __restrict__ bsum, int n) {
  __shared__ int wpart[16];
  __shared__ int wpre[16];
  int tid = threadIdx.x, lane = tid & 63, wid = tid >> 6;
  int i = blockIdx.x * 1024 + tid;
  int v = (i < n) ? deg[i] : 0;
  int x = v;
  #pragma unroll
  for (int o = 1; o < 64; o <<= 1) {
    int y = __shfl_up(x, o);
    if (lane >= o) x += y;
  }
  if (lane == 63) wpart[wid] = x;
  __syncthreads();
  if (tid == 0) {
    int run = 0;
    #pragma unroll
    for (int w = 0; w < 16; w++) { int t = wpart[w]; wpre[w] = run; run += t; }
    bsum[blockIdx.x] = run;
  }
  __syncthreads();
  if (i < n) off[i] = x - v + wpre[wid];
}

__global__ void scan2_k(const int* __restrict__ bsum, int* __restrict__ bpre,
                        int* __restrict__ off, int nb, int n) {
  if (threadIdx.x == 0) {
    int run = 0;
    for (int b = 0; b < nb; b++) { int t = bsum[b]; bpre[b] = run; run += t; }
    off[n] = run;
  }
}

__global__ __launch_bounds__(1024) void scan3_k(int* __restrict__ off,
                                                const int* __restrict__ bpre, int n) {
  int i = blockIdx.x * 1024 + threadIdx.x;
  if (i < n) off[i] += bpre[blockIdx.x];
}

__global__ void fill_k(const int* __restrict__ ei, const int* __restrict__ off,
                       const int* __restrict__ rank, int* __restrict__ csr, int E) {
  int e = blockIdx.x * blockDim.x + threadIdx.x;
  if (e < E) {
    int d = ei[E + e];
    int p = off[d] + rank[e];
    __builtin_nontemporal_store(ei[e], &csr[p]);
  }
}

// ---------------- mean aggregation: 8 nodes/wave, 8 lanes x uint4 per row ----
// One load instruction gathers 8 full 128B rows; unroll-8 keeps 8x16B per lane
// in flight. No LDS, ~60 VGPR -> full occupancy.

__global__ __launch_bounds__(256) void agg_k(
    const ushort* __restrict__ Xb, const int* __restrict__ off, const int* __restrict__ csr,
    ushort* __restrict__ aggout, int n) {
  int lane = threadIdx.x & 63;
  int oct = lane >> 3, f4 = lane & 7;
  int wave = blockIdx.x * 4 + (threadIdx.x >> 6);
  int nw = gridDim.x * 4;
  const uint4* X4 = (const uint4*)Xb;
  for (int i = wave * 8 + oct; i < n + 7; i += nw * 8) {
    int ic = i < n ? i : n - 1;
    int s0 = off[ic], s1 = off[ic + 1];
    float a0 = 0.f, a1 = 0.f, a2 = 0.f, a3 = 0.f;
    float a4 = 0.f, a5 = 0.f, a6 = 0.f, a7 = 0.f;
    for (int j = s0; j < s1; j += 8) {
      int id[8]; uint4 us[8];
      #pragma unroll
      for (int u = 0; u < 8; u++) {
        int jj = j + u;
        id[u] = csr[jj < s1 ? jj : s1 - 1];
      }
      #pragma unroll
      for (int u = 0; u < 8; u++) us[u] = X4[(size_t)id[u] * 8 + f4];
      #pragma unroll
      for (int u = 0; u < 8; u++) {
        if (j + u < s1) {
          a0 += bflo(us[u].x); a1 += bfhi(us[u].x);
          a2 += bflo(us[u].y); a3 += bfhi(us[u].y);
          a4 += bflo(us[u].z); a5 += bfhi(us[u].z);
          a6 += bflo(us[u].w); a7 += bfhi(us[u].w);
        }
      }
    }
    if (i < n) {
      float rdeg = 1.f / fmaxf((float)(s1 - s0), 1.f);
      uint4 w;
      w.x = pkbf(a0 * rdeg, a1 * rdeg);
      w.y = pkbf(a2 * rdeg, a3 * rdeg);
      w.z = pkbf(a4 * rdeg, a5 * rdeg);
      w.w = pkbf(a6 * rdeg, a7 * rdeg);
      ((uint4*)aggout)[(size_t)i * 8 + f4] = w;
    }
  }
}

// ---------------- node linear + LN + relu via MFMA ----------------

__global__ __launch_bounds__(256) void node_k(
    const ushort* __restrict__ agg, const ushort* __restrict__ selfb,
    const float* __restrict__ wl, const float* __restrict__ wr,
    const float* __restrict__ bias, const float* __restrict__ g, const float* __restrict__ lb,
    ushort* __restrict__ outb, int n) {
  __shared__ ushort wt[64 * 128];   // [n][k] swizzled, 16KB
  const int tid = threadIdx.x;
  for (int i = tid; i < 8192; i += 256) {
    int k = i >> 6, nn = i & 63;
    float v = (k < 64) ? wl[k * 64 + nn] : wr[(k - 64) * 64 + nn];
    wt[nn * 128 + (((k >> 3) ^ (nn & 7)) * 8) + (k & 7)] = bfbits(v);
  }
  __syncthreads();
  const int lane = tid & 63, wid = tid >> 6;
  const int ln = lane & 15, q = lane >> 4;
  float bias_n[4], g_n[4], lb_n[4];
  #pragma unroll
  for (int nt = 0; nt < 4; nt++) {
    bias_n[nt] = bias[nt * 16 + ln];
    g_n[nt] = g[nt * 16 + ln];
    lb_n[nt] = lb[nt * 16 + ln];
  }
  const int ntiles = (n + 15) >> 4;
  for (int t = blockIdx.x * 4 + wid; t < ntiles; t += gridDim.x * 4) {
    int node = t * 16 + ln;
    int nc = node < n ? node : n - 1;
    FragU afr[4];
    #pragma unroll
    for (int kk = 0; kk < 2; kk++) {
      afr[kk].v     = ((const uint4*)agg)[(size_t)nc * 8 + kk * 4 + q];
      afr[2 + kk].v = ((const uint4*)selfb)[(size_t)nc * 8 + kk * 4 + q];
    }
    ffrag acc[4];
    #pragma unroll
    for (int nt = 0; nt < 4; nt++) acc[nt] = ffrag{0.f, 0.f, 0.f, 0.f};
    #pragma unroll
    for (int kk = 0; kk < 4; kk++) {
      bfrag a = afr[kk].f;
      #pragma unroll
      for (int nt = 0; nt < 4; nt++) {
        int nn = nt * 16 + ln;
        int b = kk * 4 + q;
        const bfrag* bp = (const bfrag*)&wt[nn * 128 + ((b ^ (nn & 7)) * 8)];
        acc[nt] = __builtin_amdgcn_mfma_f32_16x16x32_bf16(a, *bp, acc[nt], 0, 0, 0);
      }
    }
    #pragma unroll
    for (int r = 0; r < 4; r++) {
      int m = t * 16 + q * 4 + r;
      float o[4];
      #pragma unroll
      for (int nt = 0; nt < 4; nt++) o[nt] = acc[nt][r] + bias_n[nt];
      float s = (o[0] + o[1]) + (o[2] + o[3]);
      #pragma unroll
      for (int mm = 1; mm < 16; mm <<= 1) s += __shfl_xor(s, mm);
      float mu = s * (1.f / 64.f);
      float v2 = 0.f;
      #pragma unroll
      for (int nt = 0; nt < 4; nt++) { float d2 = o[nt] - mu; v2 += d2 * d2; }
      #pragma unroll
      for (int mm = 1; mm < 16; mm <<= 1) v2 += __shfl_xor(v2, mm);
      float rs = rsqrtf(v2 * (1.f / 64.f) + 1e-5f);
      if (m < n) {
        #pragma unroll
        for (int nt = 0; nt < 4; nt++) {
          float y = fmaxf((o[nt] - mu) * rs * g_n[nt] + lb_n[nt], 0.f);
          outb[(size_t)m * 64 + nt * 16 + ln] = bfbits(y);
        }
      }
    }
  }
}

// ---------------- edge classifier: operand-swapped L1, bias folded into K ----
// L1: h1^T = A(W1^T+bias row, LDS) x B(edge features, regs), K=256 (k=224 is a
// constant-1.0 activation carrying cb1). C-layout: col=edge, row=feat -> each
// lane holds 4 consecutive feats of one edge -> 4x ds_write_b64 transpose.
// L2/L3 unchanged (h1 LDS frag is the A operand).

__global__ __launch_bounds__(256, 4) void edge_mfma_k(
    const int* __restrict__ ei, const float* __restrict__ ea,
    const ushort* __restrict__ zb,
    const float* __restrict__ cw1, const float* __restrict__ cb1,
    const float* __restrict__ cw2, const float* __restrict__ cb2,
    const float* __restrict__ cw3, const float* __restrict__ cb3,
    float* __restrict__ out, int E) {
  __shared__ ushort wt1[64 * 256];      // [n][k 0..255] swizzled; k=224 -> cb1
  __shared__ ushort h1b[4][16 * 64];    // per-wave h1 [edge][feat] swizzled, 2KB
  const int tid = threadIdx.x;

  for (int i = tid; i < 64 * 256; i += 256) {
    int n = i >> 8, k = i & 255;
    float v = (k < 224) ? cw1[k * 64 + n] : (k == 224 ? cb1[n] : 0.f);
    wt1[n * 256 + (((k >> 3) ^ (n & 7)) * 8) + (k & 7)] = bfbits(v);
  }
  __syncthreads();

  const int lane = tid & 63, wid = tid >> 6;
  const int ln = lane & 15, q = lane >> 4;

  float cb2a = cb2[ln], cb2b = cb2[16 + ln];
  float w3a = cw3[ln], w3b = cw3[16 + ln];
  float cb3v = cb3[0];

  // W2^T B-fragments in registers (16 dwords)
  FragU w2f[2][2];
  #pragma unroll
  for (int t2 = 0; t2 < 2; t2++) {
    #pragma unroll
    for (int kk = 0; kk < 2; kk++) {
      #pragma unroll
      for (int p = 0; p < 4; p++) {
        int k = kk * 32 + q * 8 + p * 2;
        int n = t2 * 16 + ln;
        w2f[t2][kk].u[p] = pkbf(cw2[k * 32 + n], cw2[(k + 1) * 32 + n]);
      }
    }
  }

  const uint32_t a7lo = (q == 0) ? 0x00003F80u : 0u;  // bf16(1.0) at k=224
  ushort* hb = h1b[wid];
  const int ntiles = E >> 4;
  const int stride = gridDim.x * 4;
  int t = blockIdx.x * 4 + wid;

  FragU curz[4]; float4 ceal, ceah;
  if (t < ntiles) {
    int e = t * 16 + ln;
    int s = ei[e], d = ei[E + e];
    curz[0].v = ((const uint4*)zb)[(size_t)s * 8 + q];
    curz[1].v = ((const uint4*)zb)[(size_t)s * 8 + 4 + q];
    curz[2].v = ((const uint4*)zb)[(size_t)d * 8 + q];
    curz[3].v = ((const uint4*)zb)[(size_t)d * 8 + 4 + q];
    ceal = ((const float4*)ea)[(size_t)e * 8 + q * 2];
    ceah = ((const float4*)ea)[(size_t)e * 8 + q * 2 + 1];
  }

  for (; t < ntiles; t += stride) {
    int tn = t + stride;
    FragU nz[4]; float4 neal, neah;
    if (tn < ntiles) {
      int e2 = tn * 16 + ln;
      int s2 = ei[e2], d2 = ei[E + e2];
      nz[0].v = ((const uint4*)zb)[(size_t)s2 * 8 + q];
      nz[1].v = ((const uint4*)zb)[(size_t)s2 * 8 + 4 + q];
      nz[2].v = ((const uint4*)zb)[(size_t)d2 * 8 + q];
      nz[3].v = ((const uint4*)zb)[(size_t)d2 * 8 + 4 + q];
      neal = ((const float4*)ea)[(size_t)e2 * 8 + q * 2];
      neah = ((const float4*)ea)[(size_t)e2 * 8 + q * 2 + 1];
    }

    // B-fragments: lane (ln,q) holds feats q*8..+7 of edge ln
    FragU afr[8];
    afr[0] = curz[0]; afr[1] = curz[1]; afr[2] = curz[2]; afr[3] = curz[3];
    #pragma unroll
    for (int kk = 0; kk < 2; kk++) {
      #pragma unroll
      for (int p = 0; p < 4; p++)
        afr[4 + kk].u[p] = mul2bf(curz[kk].u[p], curz[2 + kk].u[p]);
    }
    afr[6].u[0] = pkbf(ceal.x, ceal.y); afr[6].u[1] = pkbf(ceal.z, ceal.w);
    afr[6].u[2] = pkbf(ceah.x, ceah.y); afr[6].u[3] = pkbf(ceah.z, ceah.w);
    afr[7].u[0] = a7lo; afr[7].u[1] = 0; afr[7].u[2] = 0; afr[7].u[3] = 0;

    // L1: D[m=feat][n=edge], A = wt1 rows (LDS), B = afr
    ffrag acc1[4];
    #pragma unroll
    for (int mt = 0; mt < 4; mt++) acc1[mt] = ffrag{0.f, 0.f, 0.f, 0.f};
    #pragma unroll
    for (int kk = 0; kk < 8; kk++) {
      bfrag b = afr[kk].f;
      #pragma unroll
      for (int mt = 0; mt < 4; mt++) {
        int m = mt * 16 + ln;
        const bfrag* ap = (const bfrag*)&wt1[m * 256 + (((kk * 4 + q) ^ (ln & 7)) * 8)];
        acc1[mt] = __builtin_amdgcn_mfma_f32_16x16x32_bf16(*ap, b, acc1[mt], 0, 0, 0);
      }
    }

    // h1 = relu(acc1): lane holds feats mt*16+q*4..+3 of edge ln -> b64 writes
    #pragma unroll
    for (int mt = 0; mt < 4; mt++) {
      float v0 = fmaxf(acc1[mt][0], 0.f), v1 = fmaxf(acc1[mt][1], 0.f);
      float v2 = fmaxf(acc1[mt][2], 0.f), v3 = fmaxf(acc1[mt][3], 0.f);
      uint2 w; w.x = pkbf(v0, v1); w.y = pkbf(v2, v3);
      int blk = (mt * 2 + (q >> 1)) ^ (ln & 7);
      *(uint2*)&hb[ln * 64 + blk * 8 + (q & 1) * 4] = w;
    }

    // L2: h2 = h1 * W2 (A = h1 frag from LDS, same lane map)
    ffrag acc2[2];
    acc2[0] = ffrag{0.f, 0.f, 0.f, 0.f};
    acc2[1] = ffrag{0.f, 0.f, 0.f, 0.f};
    #pragma unroll
    for (int kk = 0; kk < 2; kk++) {
      const bfrag* ap = (const bfrag*)&hb[ln * 64 + (((kk * 4 + q) ^ (ln & 7)) * 8)];
      bfrag a2 = *ap;
      acc2[0] = __builtin_amdgcn_mfma_f32_16x16x32_bf16(a2, w2f[0][kk].f, acc2[0], 0, 0, 0);
      acc2[1] = __builtin_amdgcn_mfma_f32_16x16x32_bf16(a2, w2f[1][kk].f, acc2[1], 0, 0, 0);
    }

    float p0, p1, p2, p3;
    {
      p0 = fmaxf(acc2[0][0] + cb2a, 0.f) * w3a + fmaxf(acc2[1][0] + cb2b, 0.f) * w3b;
      p1 = fmaxf(acc2[0][1] + cb2a, 0.f) * w3a + fmaxf(acc2[1][1] + cb2b, 0.f) * w3b;
      p2 = fmaxf(acc2[0][2] + cb2a, 0.f) * w3a + fmaxf(acc2[1][2] + cb2b, 0.f) * w3b;
      p3 = fmaxf(acc2[0][3] + cb2a, 0.f) * w3a + fmaxf(acc2[1][3] + cb2b, 0.f) * w3b;
    }
    #pragma unroll
    for (int o = 1; o < 16; o <<= 1) {
      p0 += __shfl_xor(p0, o);
      p1 += __shfl_xor(p1, o);
      p2 += __shfl_xor(p2, o);
      p3 += __shfl_xor(p3, o);
    }
    float keep = (ln == 0) ? p0 : (ln == 1) ? p1 : (ln == 2) ? p2 : p3;
    if (ln < 4) out[t * 16 + q * 4 + ln] = keep + cb3v;

    curz[0] = nz[0]; curz[1] = nz[1]; curz[2] = nz[2]; curz[3] = nz[3];
    ceal = neal; ceah = neah;
  }
}

// ---------------- launch ----------------

extern "C" void kernel_launch(void* const* d_in, const int* in_sizes, int n_in,
                              void* d_out, int out_size, void* d_ws, size_t ws_size,
                              hipStream_t stream) {
  const float* x   = (const float*)d_in[0];
  const int*   ei  = (const int*)d_in[1];
  const float* ea  = (const float*)d_in[2];
  const float* wl0 = (const float*)d_in[3];
  const float* wr0 = (const float*)d_in[4];
  const float* b0  = (const float*)d_in[5];
  const float* g0  = (const float*)d_in[6];
  const float* lb0 = (const float*)d_in[7];
  const float* wl1 = (const float*)d_in[8];
  const float* wr1 = (const float*)d_in[9];
  const float* b1  = (const float*)d_in[10];
  const float* g1  = (const float*)d_in[11];
  const float* lb1 = (const float*)d_in[12];
  const float* cw1 = (const float*)d_in[13];
  const float* cb1 = (const float*)d_in[14];
  const float* cw2 = (const float*)d_in[15];
  const float* cb2 = (const float*)d_in[16];
  const float* cw3 = (const float*)d_in[17];
  const float* cb3 = (const float*)d_in[18];
  float* out = (float*)d_out;
  const int N = N_NODES, E = N_EDGES;
  const int NB = (N + 1023) / 1024;

  uintptr_t pp = (uintptr_t)d_ws;
  auto alloc = [&](size_t bytes) {
    uintptr_t r = (pp + 255) & ~(uintptr_t)255; pp = r + bytes; return (void*)r;
  };
  int* deg  = (int*)alloc((size_t)N * 4);
  int* off  = (int*)alloc((size_t)(N + 1) * 4);
  int* rank = (int*)alloc((size_t)E * 4);
  int* csr  = (int*)alloc((size_t)E * 4);
  int* bsum = (int*)alloc((size_t)NB * 4);
  int* bpre = (int*)alloc((size_t)NB * 4);
  ushort* xb  = (ushort*)alloc((size_t)N * 64 * 2);
  ushort* agg = (ushort*)alloc((size_t)N * 64 * 2);
  ushort* hb  = (ushort*)alloc((size_t)N * 64 * 2);
  ushort* zb  = (ushort*)alloc((size_t)N * 64 * 2);

  hipMemsetAsync(deg, 0, (size_t)N * 4, stream);
  cvt_k<<<(N * 32 + 255) / 256, 256, 0, stream>>>(x, xb, N * 32);
  hist_k<<<(E + 255) / 256, 256, 0, stream>>>(ei, deg, rank, E);
  scan1_k<<<NB, 1024, 0, stream>>>(deg, off, bsum, N);
  scan2_k<<<1, 64, 0, stream>>>(bsum, bpre, off, NB, N);
  scan3_k<<<NB, 1024, 0, stream>>>(off, bpre, N);
  fill_k<<<(E + 255) / 256, 256, 0, stream>>>(ei, off, rank, csr, E);
  // layer 0
  agg_k<<<3136, 256, 0, stream>>>(xb, off, csr, agg, N);
  node_k<<<512, 256, 0, stream>>>(agg, xb, wl0, wr0, b0, g0, lb0, hb, N);
  // layer 1
  agg_k<<<3136, 256, 0, stream>>>(hb, off, csr, agg, N);
  node_k<<<512, 256, 0, stream>>>(agg, hb, wl1, wr1, b1, g1, lb1, zb, N);
  // edge classifier
  edge_mfma_k<<<1024, 256, 0, stream>>>(ei, ea, zb, cw1, cb1, cw2, cb2, cw3, cb3, out, E);
}